// Round 8
// baseline (613.656 us; speedup 1.0000x reference)
//
#include <hip/hip_runtime.h>

#define NUM_NODES 100000
#define EMB_DIM   64
#define NUM_LAYERS 3
#define NUM_EDGES 3200000
#define NUM_QUERY 1000000

#define BSHIFT   6
#define BNODES   64                                    // nodes per bucket
#define NBUCKETS ((NUM_NODES + BNODES - 1) / BNODES)   // 1563
#define SRC_MASK 131071                                // 17 bits (NUM_NODES < 2^17)
#define NCHUNK   128
#define CHUNK    (NUM_EDGES / NCHUNK)                  // 25000 edges per chunk

// ---------------------------------------------------------------------------
// Per-chunk bucket histogram in LDS -> hist_g[chunk][bucket], key = keys[i]>>6
__global__ __launch_bounds__(256) void chist_kernel(const int* __restrict__ keys,
                                                    int* __restrict__ hist_g) {
    __shared__ int h[NBUCKETS];
    int b = blockIdx.x, tid = threadIdx.x;
    for (int k = tid; k < NBUCKETS; k += 256) h[k] = 0;
    __syncthreads();
    int beg = b * CHUNK, end = beg + CHUNK;
    for (int i = beg + tid; i < end; i += 256)
        atomicAdd(&h[keys[i] >> BSHIFT], 1);
    __syncthreads();
    for (int k = tid; k < NBUCKETS; k += 256)
        hist_g[b * NBUCKETS + k] = h[k];
}

// Per-bucket exclusive scan across the 128 chunks (one wave per bucket, in place).
// Also emits bucket totals.
__global__ void bscan_kernel(int* __restrict__ hist_g, int* __restrict__ bcnt) {
    int gw   = (blockIdx.x * blockDim.x + threadIdx.x) >> 6;
    int lane = threadIdx.x & 63;
    if (gw >= NBUCKETS) return;
    int c0 = 2 * lane, c1 = 2 * lane + 1;
    int v0 = hist_g[c0 * NBUCKETS + gw];
    int v1 = hist_g[c1 * NBUCKETS + gw];
    int pair = v0 + v1, x = pair;
    #pragma unroll
    for (int d = 1; d < 64; d <<= 1) {
        int y = __shfl_up(x, d);
        if (lane >= d) x += y;
    }
    int ex = x - pair;                    // exclusive prefix over chunks
    hist_g[c0 * NBUCKETS + gw] = ex;
    hist_g[c1 * NBUCKETS + gw] = ex + v0;
    if (lane == 63) bcnt[gw] = x;         // bucket total
}

// single-block scan over NBUCKETS (2 tiles): boffs[b+1] = inclusive sum
__global__ void scan_kernel(const int* __restrict__ bcnt, int* __restrict__ boffs) {
    __shared__ int tile[1024];
    __shared__ int carry;
    int t = threadIdx.x;
    if (t == 0) { carry = 0; boffs[0] = 0; }
    __syncthreads();
    for (int base = 0; base < NBUCKETS; base += 1024) {
        int v = (base + t < NBUCKETS) ? bcnt[base + t] : 0;
        tile[t] = v;
        __syncthreads();
        for (int d = 1; d < 1024; d <<= 1) {
            int add = (t >= d) ? tile[t - d] : 0;
            __syncthreads();
            tile[t] += add;
            __syncthreads();
        }
        int inc = tile[t] + carry;
        if (base + t < NBUCKETS) boffs[base + t + 1] = inc;
        __syncthreads();
        if (t == 1023) carry = inc;
        __syncthreads();
    }
}

// Pass A scatter: src-major coarse sort, writes (src_a, dst_a) pairs.
// LDS cursors -> every (chunk,bucket) segment written by exactly one block.
__global__ __launch_bounds__(256) void cscatter2_kernel(
        const int* __restrict__ src, const int* __restrict__ dst,
        const int* __restrict__ boffs, const int* __restrict__ hist_g,
        int* __restrict__ src_a, int* __restrict__ dst_a) {
    __shared__ int cur[NBUCKETS];
    int b = blockIdx.x, tid = threadIdx.x;
    for (int k = tid; k < NBUCKETS; k += 256)
        cur[k] = boffs[k] + hist_g[b * NBUCKETS + k];
    __syncthreads();
    int beg = b * CHUNK, end = beg + CHUNK;
    for (int i = beg + tid; i < end; i += 256) {
        int s = src[i], d = dst[i];
        int pos = atomicAdd(&cur[s >> BSHIFT], 1);
        src_a[pos] = s;
        dst_a[pos] = d;
    }
}

// Pass B scatter: dst-major, input already src-ordered (chunk order preserves it).
__global__ __launch_bounds__(256) void cscatter_kernel(
        const int* __restrict__ src, const int* __restrict__ dst,
        const int* __restrict__ boffs, const int* __restrict__ hist_g,
        int* __restrict__ packed) {
    __shared__ int cur[NBUCKETS];
    int b = blockIdx.x, tid = threadIdx.x;
    for (int k = tid; k < NBUCKETS; k += 256)
        cur[k] = boffs[k] + hist_g[b * NBUCKETS + k];
    __syncthreads();
    int beg = b * CHUNK, end = beg + CHUNK;
    for (int i = beg + tid; i < end; i += 256) {
        int s = src[i], d = dst[i];
        int pos = atomicAdd(&cur[d >> BSHIFT], 1);
        packed[pos] = s | ((d & 63) << 17);
    }
}

// per-bucket local counting sort -> exact per-node CSR (src_srt, offs) + dis
__global__ __launch_bounds__(256) void lsort_kernel(
        const int* __restrict__ boffs, const int* __restrict__ packed,
        int* __restrict__ offs, int* __restrict__ src_srt, float* __restrict__ dis) {
    __shared__ int cnt[BNODES];
    int b   = blockIdx.x;
    int tid = threadIdx.x;
    int beg = boffs[b];
    int end = boffs[b + 1];
    if (tid < BNODES) cnt[tid] = 0;
    __syncthreads();
    for (int i = beg + tid; i < end; i += 256)
        atomicAdd(&cnt[(packed[i] >> 17) & 63], 1);
    __syncthreads();
    if (tid < 64) {                      // wave 0: exclusive scan of 64 counters
        int v = cnt[tid];
        int x = v;
        #pragma unroll
        for (int d = 1; d < 64; d <<= 1) {
            int y = __shfl_up(x, d);
            if (tid >= d) x += y;
        }
        int ex = x - v;                  // exclusive prefix
        int node = (b << BSHIFT) + tid;
        if (node <= NUM_NODES) offs[node] = beg + ex;   // bucket 1562/tid 32 writes offs[N]=E
        if (node <  NUM_NODES) dis[node] = (v > 0) ? rsqrtf((float)v) : 0.0f;
        cnt[tid] = ex;                   // reuse as local cursor
    }
    __syncthreads();
    for (int i = beg + tid; i < end; i += 256) {
        int p  = packed[i];
        int pos = beg + atomicAdd(&cnt[(p >> 17) & 63], 1);
        src_srt[pos] = p & SRC_MASK;
    }
}

// y = dis ⊙ emb (row-wise scale), float4 vectorized
__global__ void prescale_kernel(const float4* __restrict__ emb4, const float* __restrict__ dis,
                                float4* __restrict__ y4) {
    int i = blockIdx.x * blockDim.x + threadIdx.x;
    int stride = gridDim.x * blockDim.x;
    const int n4 = NUM_NODES * EMB_DIM / 4;
    for (; i < n4; i += stride) {
        float d = dis[i >> 4];               // 16 float4s per row
        float4 v = emb4[i];
        v.x *= d; v.y *= d; v.z *= d; v.w *= d;
        y4[i] = v;
    }
}

// ---------------------------------------------------------------------------
// Wave per node, lane = dim, exact CSR gather, zero atomics, y-space.
// Adjacency lists are src-ascending (stable sort) -> concurrent waves gather
// from a narrow src window -> L2-resident.
//  mode 0: yout = dn*dn*acc; outw = alpha*(emb + dn*acc)
//  mode 1: yout = dn*dn*acc; outw += alpha*dn*acc
//  mode 2:                   outw += alpha*dn*acc
__global__ __launch_bounds__(256) void prop_kernel(
        const int* __restrict__ offs, const int* __restrict__ src_s,
        const float* __restrict__ dis, const float* __restrict__ yin,
        float* __restrict__ yout, const float* __restrict__ emb,
        float* __restrict__ outw, float alpha, int mode) {
    int wid  = (blockIdx.x * blockDim.x + threadIdx.x) >> 6;
    int lane = threadIdx.x & 63;
    if (wid >= NUM_NODES) return;
    int beg = offs[wid];
    int end = offs[wid + 1];
    float acc = 0.0f;
    int j = beg;
    // 8-deep gather pipeline
    for (; j + 8 <= end; j += 8) {
        int s0 = src_s[j];     int s1 = src_s[j + 1];
        int s2 = src_s[j + 2]; int s3 = src_s[j + 3];
        int s4 = src_s[j + 4]; int s5 = src_s[j + 5];
        int s6 = src_s[j + 6]; int s7 = src_s[j + 7];
        float v0 = yin[(s0 << 6) + lane];
        float v1 = yin[(s1 << 6) + lane];
        float v2 = yin[(s2 << 6) + lane];
        float v3 = yin[(s3 << 6) + lane];
        float v4 = yin[(s4 << 6) + lane];
        float v5 = yin[(s5 << 6) + lane];
        float v6 = yin[(s6 << 6) + lane];
        float v7 = yin[(s7 << 6) + lane];
        acc += ((v0 + v1) + (v2 + v3)) + ((v4 + v5) + (v6 + v7));
    }
    for (; j < end; ++j) acc += yin[(src_s[j] << 6) + lane];

    float dn = dis[wid];
    float x  = dn * acc;                 // x_{l+1}
    int o = (wid << 6) + lane;
    if (mode == 0) {
        yout[o] = dn * x;
        outw[o] = alpha * (emb[o] + x);
    } else if (mode == 1) {
        yout[o] = dn * x;
        outw[o] += alpha * x;
    } else {
        outw[o] += alpha * x;
    }
}

// 16 queries per wave, 4 lanes per query, float4 row loads.
__global__ __launch_bounds__(256) void score_kernel(
        const int* __restrict__ qa, const int* __restrict__ qb,
        const float4* __restrict__ x4, float* __restrict__ res) {
    int wave = (blockIdx.x * blockDim.x + threadIdx.x) >> 6;
    int lane = threadIdx.x & 63;
    int g = lane >> 2;                   // query slot in wave (0..15)
    int k = lane & 3;                    // chunk lane (0..3)
    int q = (wave << 4) + g;
    int a = qa[q];
    int b = qb[q];
    const float4* pa = x4 + (a << 4);    // 16 float4s per row
    const float4* pb = x4 + (b << 4);
    float4 a0 = pa[k];      float4 b0 = pb[k];
    float4 a1 = pa[4 + k];  float4 b1 = pb[4 + k];
    float4 a2 = pa[8 + k];  float4 b2 = pb[8 + k];
    float4 a3 = pa[12 + k]; float4 b3 = pb[12 + k];
    float p = a0.x * b0.x;
    p = fmaf(a0.y, b0.y, p); p = fmaf(a0.z, b0.z, p); p = fmaf(a0.w, b0.w, p);
    p = fmaf(a1.x, b1.x, p); p = fmaf(a1.y, b1.y, p);
    p = fmaf(a1.z, b1.z, p); p = fmaf(a1.w, b1.w, p);
    p = fmaf(a2.x, b2.x, p); p = fmaf(a2.y, b2.y, p);
    p = fmaf(a2.z, b2.z, p); p = fmaf(a2.w, b2.w, p);
    p = fmaf(a3.x, b3.x, p); p = fmaf(a3.y, b3.y, p);
    p = fmaf(a3.z, b3.z, p); p = fmaf(a3.w, b3.w, p);
    p += __shfl_xor(p, 1);
    p += __shfl_xor(p, 2);
    if (k == 0) res[q] = p;
}

extern "C" void kernel_launch(void* const* d_in, const int* in_sizes, int n_in,
                              void* d_out, int out_size, void* d_ws, size_t ws_size,
                              hipStream_t stream) {
    const float* emb  = (const float*)d_in[0];
    const int*   edge = (const int*)d_in[1];   // [2][NUM_EDGES]: src then dst
    const int*   qidx = (const int*)d_in[2];   // [2][NUM_QUERY]
    float*       out  = (float*)d_out;         // [NUM_QUERY]

    const int* e_src = edge;
    const int* e_dst = edge + NUM_EDGES;
    const int* q_a   = qidx;
    const int* q_b   = qidx + NUM_QUERY;

    const size_t XBYTES = (size_t)NUM_NODES * EMB_DIM * sizeof(float); // 25.6 MB
    char* ws = (char*)d_ws;
    size_t off = 0;
    auto carve = [&](size_t bytes) { void* p = ws + off; off += (bytes + 255) & ~(size_t)255; return p; };
    int*   hist_g  = (int*)  carve((size_t)NCHUNK * NBUCKETS * 4);   // 800 KB (reused A/B)
    int*   bcnt    = (int*)  carve((size_t)NBUCKETS * 4);
    int*   boffs   = (int*)  carve((size_t)(NBUCKETS + 1) * 4);      // reused A/B
    int*   offs    = (int*)  carve((size_t)(NUM_NODES + 1) * 4);
    float* dis     = (float*)carve((size_t)NUM_NODES * 4);
    int*   src_a   = (int*)  carve((size_t)NUM_EDGES * 4);   // 12.8 MB (later src_srt)
    int*   dst_a   = (int*)  carve((size_t)NUM_EDGES * 4);   // 12.8 MB
    int*   packed  = (int*)  carve((size_t)NUM_EDGES * 4);   // 12.8 MB
    float* yA      = (float*)carve(XBYTES);
    float* yB      = (float*)carve(XBYTES);
    float* outw    = (float*)carve(XBYTES);
    int*   src_srt = src_a;              // pass-A buffer dead after cscatter_kernel

    const float alpha = 1.0f / (NUM_LAYERS + 1);   // 0.25

    // ---- Pass A: coarse src-major sort (stable clustering for L2 reuse)
    chist_kernel<<<NCHUNK, 256, 0, stream>>>(e_src, hist_g);
    bscan_kernel<<<(NBUCKETS * 64 + 255) / 256, 256, 0, stream>>>(hist_g, bcnt);
    scan_kernel<<<1, 1024, 0, stream>>>(bcnt, boffs);
    cscatter2_kernel<<<NCHUNK, 256, 0, stream>>>(e_src, e_dst, boffs, hist_g, src_a, dst_a);

    // ---- Pass B: dst-major sort of the src-ordered list -> per-node CSR
    chist_kernel<<<NCHUNK, 256, 0, stream>>>(dst_a, hist_g);
    bscan_kernel<<<(NBUCKETS * 64 + 255) / 256, 256, 0, stream>>>(hist_g, bcnt);
    scan_kernel<<<1, 1024, 0, stream>>>(bcnt, boffs);
    cscatter_kernel<<<NCHUNK, 256, 0, stream>>>(src_a, dst_a, boffs, hist_g, packed);
    lsort_kernel<<<NBUCKETS, 256, 0, stream>>>(boffs, packed, offs, src_srt, dis);
    prescale_kernel<<<2048, 256, 0, stream>>>((const float4*)emb, dis, (float4*)yA);

    // ---- 3 propagation layers (y-space), out-accumulation fused
    const int PROP_BLOCKS = (NUM_NODES * 64 + 255) / 256;
    prop_kernel<<<PROP_BLOCKS, 256, 0, stream>>>(offs, src_srt, dis, yA, yB, emb, outw, alpha, 0);
    prop_kernel<<<PROP_BLOCKS, 256, 0, stream>>>(offs, src_srt, dis, yB, yA, emb, outw, alpha, 1);
    prop_kernel<<<PROP_BLOCKS, 256, 0, stream>>>(offs, src_srt, dis, yA, yB, emb, outw, alpha, 2);

    // ---- scoring: 64 queries per 256-thread block (16 per wave)
    score_kernel<<<NUM_QUERY / 64, 256, 0, stream>>>(q_a, q_b, (const float4*)outw, out);
}

// Round 9
// 607.346 us; speedup vs baseline: 1.0104x; 1.0104x over previous
//
#include <hip/hip_runtime.h>

#define NUM_NODES 100000
#define EMB_DIM   64
#define NUM_LAYERS 3
#define NUM_EDGES 3200000
#define NUM_QUERY 1000000

#define BSHIFT   6
#define BNODES   64                                    // nodes per bucket
#define NBUCKETS ((NUM_NODES + BNODES - 1) / BNODES)   // 1563
#define SRC_MASK 131071                                // 17 bits (NUM_NODES < 2^17)
#define NCHUNK   128
#define CHUNK    (NUM_EDGES / NCHUNK)                  // 25000 edges per chunk

#define DCHUNKS  64
#define DNODES   ((NUM_NODES + DCHUNKS - 1) / DCHUNKS) // 1563 nodes per deg-chunk
#define DBINS    128                                   // degree bins (clamped)

// ---------------------------------------------------------------------------
// Per-chunk bucket histogram in LDS -> hist_g[chunk][bucket], key = keys[i]>>6
__global__ __launch_bounds__(256) void chist_kernel(const int* __restrict__ keys,
                                                    int* __restrict__ hist_g) {
    __shared__ int h[NBUCKETS];
    int b = blockIdx.x, tid = threadIdx.x;
    for (int k = tid; k < NBUCKETS; k += 256) h[k] = 0;
    __syncthreads();
    int beg = b * CHUNK, end = beg + CHUNK;
    for (int i = beg + tid; i < end; i += 256)
        atomicAdd(&h[keys[i] >> BSHIFT], 1);
    __syncthreads();
    for (int k = tid; k < NBUCKETS; k += 256)
        hist_g[b * NBUCKETS + k] = h[k];
}

// Same, but key = pairs[i].y (dst of an int2 pair)
__global__ __launch_bounds__(256) void chist_pairs_kernel(const int2* __restrict__ pairs,
                                                          int* __restrict__ hist_g) {
    __shared__ int h[NBUCKETS];
    int b = blockIdx.x, tid = threadIdx.x;
    for (int k = tid; k < NBUCKETS; k += 256) h[k] = 0;
    __syncthreads();
    int beg = b * CHUNK, end = beg + CHUNK;
    for (int i = beg + tid; i < end; i += 256)
        atomicAdd(&h[pairs[i].y >> BSHIFT], 1);
    __syncthreads();
    for (int k = tid; k < NBUCKETS; k += 256)
        hist_g[b * NBUCKETS + k] = h[k];
}

// Per-bucket exclusive scan across the 128 chunks (one wave per bucket, in place).
__global__ void bscan_kernel(int* __restrict__ hist_g, int* __restrict__ bcnt) {
    int gw   = (blockIdx.x * blockDim.x + threadIdx.x) >> 6;
    int lane = threadIdx.x & 63;
    if (gw >= NBUCKETS) return;
    int c0 = 2 * lane, c1 = 2 * lane + 1;
    int v0 = hist_g[c0 * NBUCKETS + gw];
    int v1 = hist_g[c1 * NBUCKETS + gw];
    int pair = v0 + v1, x = pair;
    #pragma unroll
    for (int d = 1; d < 64; d <<= 1) {
        int y = __shfl_up(x, d);
        if (lane >= d) x += y;
    }
    int ex = x - pair;                    // exclusive prefix over chunks
    hist_g[c0 * NBUCKETS + gw] = ex;
    hist_g[c1 * NBUCKETS + gw] = ex + v0;
    if (lane == 63) bcnt[gw] = x;         // bucket total
}

// single-block scan over NBUCKETS (2 tiles): boffs[b+1] = inclusive sum
__global__ void scan_kernel(const int* __restrict__ bcnt, int* __restrict__ boffs) {
    __shared__ int tile[1024];
    __shared__ int carry;
    int t = threadIdx.x;
    if (t == 0) { carry = 0; boffs[0] = 0; }
    __syncthreads();
    for (int base = 0; base < NBUCKETS; base += 1024) {
        int v = (base + t < NBUCKETS) ? bcnt[base + t] : 0;
        tile[t] = v;
        __syncthreads();
        for (int d = 1; d < 1024; d <<= 1) {
            int add = (t >= d) ? tile[t - d] : 0;
            __syncthreads();
            tile[t] += add;
            __syncthreads();
        }
        int inc = tile[t] + carry;
        if (base + t < NBUCKETS) boffs[base + t + 1] = inc;
        __syncthreads();
        if (t == 1023) carry = inc;
        __syncthreads();
    }
}

// Pass A scatter: src-major coarse sort, single int2 store per edge.
__global__ __launch_bounds__(256) void cscatter2_kernel(
        const int* __restrict__ src, const int* __restrict__ dst,
        const int* __restrict__ boffs, const int* __restrict__ hist_g,
        int2* __restrict__ pairs) {
    __shared__ int cur[NBUCKETS];
    int b = blockIdx.x, tid = threadIdx.x;
    for (int k = tid; k < NBUCKETS; k += 256)
        cur[k] = boffs[k] + hist_g[b * NBUCKETS + k];
    __syncthreads();
    int beg = b * CHUNK, end = beg + CHUNK;
    for (int i = beg + tid; i < end; i += 256) {
        int s = src[i], d = dst[i];
        int pos = atomicAdd(&cur[s >> BSHIFT], 1);
        pairs[pos] = make_int2(s, d);
    }
}

// Pass B scatter: dst-major over the src-ordered pair list.
__global__ __launch_bounds__(256) void cscatter_kernel(
        const int2* __restrict__ pairs,
        const int* __restrict__ boffs, const int* __restrict__ hist_g,
        int* __restrict__ packed) {
    __shared__ int cur[NBUCKETS];
    int b = blockIdx.x, tid = threadIdx.x;
    for (int k = tid; k < NBUCKETS; k += 256)
        cur[k] = boffs[k] + hist_g[b * NBUCKETS + k];
    __syncthreads();
    int beg = b * CHUNK, end = beg + CHUNK;
    for (int i = beg + tid; i < end; i += 256) {
        int2 p = pairs[i];
        int pos = atomicAdd(&cur[p.y >> BSHIFT], 1);
        packed[pos] = p.x | ((p.y & 63) << 17);
    }
}

// per-bucket local counting sort -> per-node CSR (src_srt, offs) + dis + deg
__global__ __launch_bounds__(256) void lsort_kernel(
        const int* __restrict__ boffs, const int* __restrict__ packed,
        int* __restrict__ offs, int* __restrict__ src_srt, float* __restrict__ dis,
        int* __restrict__ deg_n) {
    __shared__ int cnt[BNODES];
    int b   = blockIdx.x;
    int tid = threadIdx.x;
    int beg = boffs[b];
    int end = boffs[b + 1];
    if (tid < BNODES) cnt[tid] = 0;
    __syncthreads();
    for (int i = beg + tid; i < end; i += 256)
        atomicAdd(&cnt[(packed[i] >> 17) & 63], 1);
    __syncthreads();
    if (tid < 64) {                      // wave 0: exclusive scan of 64 counters
        int v = cnt[tid];
        int x = v;
        #pragma unroll
        for (int d = 1; d < 64; d <<= 1) {
            int y = __shfl_up(x, d);
            if (tid >= d) x += y;
        }
        int ex = x - v;                  // exclusive prefix
        int node = (b << BSHIFT) + tid;
        if (node <= NUM_NODES) offs[node] = beg + ex;
        if (node <  NUM_NODES) {
            dis[node]   = (v > 0) ? rsqrtf((float)v) : 0.0f;
            deg_n[node] = v;
        }
        cnt[tid] = ex;                   // reuse as local cursor
    }
    __syncthreads();
    for (int i = beg + tid; i < end; i += 256) {
        int p  = packed[i];
        int pos = beg + atomicAdd(&cnt[(p >> 17) & 63], 1);
        src_srt[pos] = p & SRC_MASK;
    }
}

// ---------------------------------------------------------------------------
// Degree-grouped node permutation: counting sort of nodes by clamped degree.
__global__ __launch_bounds__(256) void dhist_kernel(const int* __restrict__ deg_n,
                                                    int* __restrict__ dh) {
    __shared__ int h[DBINS];
    int b = blockIdx.x, tid = threadIdx.x;
    if (tid < DBINS) h[tid] = 0;
    __syncthreads();
    int beg = b * DNODES, end = min(beg + DNODES, NUM_NODES);
    for (int i = beg + tid; i < end; i += 256)
        atomicAdd(&h[min(deg_n[i], DBINS - 1)], 1);
    __syncthreads();
    if (tid < DBINS) dh[b * DBINS + tid] = h[tid];
}

// single block, 128 threads: in-place exclusive positions for dh[chunk][bin]
__global__ __launch_bounds__(128) void dscan_kernel(int* __restrict__ dh) {
    __shared__ int tot[DBINS];
    __shared__ int base[DBINS];
    int b = threadIdx.x;                 // bin id
    int s = 0;
    for (int c = 0; c < DCHUNKS; ++c) s += dh[c * DBINS + b];
    tot[b] = s;
    __syncthreads();
    if (b == 0) {
        int acc = 0;
        for (int i = 0; i < DBINS; ++i) { base[i] = acc; acc += tot[i]; }
    }
    __syncthreads();
    int run = base[b];
    for (int c = 0; c < DCHUNKS; ++c) {
        int v = dh[c * DBINS + b];
        dh[c * DBINS + b] = run;
        run += v;
    }
}

__global__ __launch_bounds__(256) void dscatter_kernel(const int* __restrict__ deg_n,
                                                       const int* __restrict__ dh,
                                                       int* __restrict__ perm) {
    __shared__ int cur[DBINS];
    int b = blockIdx.x, tid = threadIdx.x;
    if (tid < DBINS) cur[tid] = dh[b * DBINS + tid];
    __syncthreads();
    int beg = b * DNODES, end = min(beg + DNODES, NUM_NODES);
    for (int i = beg + tid; i < end; i += 256) {
        int pos = atomicAdd(&cur[min(deg_n[i], DBINS - 1)], 1);
        perm[pos] = i;
    }
}

// y = dis ⊙ emb (row-wise scale), float4 vectorized
__global__ void prescale_kernel(const float4* __restrict__ emb4, const float* __restrict__ dis,
                                float4* __restrict__ y4) {
    int i = blockIdx.x * blockDim.x + threadIdx.x;
    int stride = gridDim.x * blockDim.x;
    const int n4 = NUM_NODES * EMB_DIM / 4;
    for (; i < n4; i += stride) {
        float d = dis[i >> 4];               // 16 float4s per row
        float4 v = emb4[i];
        v.x *= d; v.y *= d; v.z *= d; v.w *= d;
        y4[i] = v;
    }
}

// ---------------------------------------------------------------------------
// Wave per node (degree-grouped via perm), lane = dim, CSR gather, y-space.
// Concurrent waves: equal degree + src-ascending lists -> tight L2 window.
//  mode 0: yout = dn*dn*acc; outw = alpha*(emb + dn*acc)
//  mode 1: yout = dn*dn*acc; outw += alpha*dn*acc
//  mode 2:                   outw += alpha*dn*acc
__global__ __launch_bounds__(256) void prop_kernel(
        const int* __restrict__ perm,
        const int* __restrict__ offs, const int* __restrict__ src_s,
        const float* __restrict__ dis, const float* __restrict__ yin,
        float* __restrict__ yout, const float* __restrict__ emb,
        float* __restrict__ outw, float alpha, int mode) {
    int wid  = (blockIdx.x * blockDim.x + threadIdx.x) >> 6;
    int lane = threadIdx.x & 63;
    if (wid >= NUM_NODES) return;
    int node = perm[wid];
    int beg = offs[node];
    int end = offs[node + 1];
    float acc = 0.0f;
    int j = beg;
    // 8-deep gather pipeline
    for (; j + 8 <= end; j += 8) {
        int s0 = src_s[j];     int s1 = src_s[j + 1];
        int s2 = src_s[j + 2]; int s3 = src_s[j + 3];
        int s4 = src_s[j + 4]; int s5 = src_s[j + 5];
        int s6 = src_s[j + 6]; int s7 = src_s[j + 7];
        float v0 = yin[(s0 << 6) + lane];
        float v1 = yin[(s1 << 6) + lane];
        float v2 = yin[(s2 << 6) + lane];
        float v3 = yin[(s3 << 6) + lane];
        float v4 = yin[(s4 << 6) + lane];
        float v5 = yin[(s5 << 6) + lane];
        float v6 = yin[(s6 << 6) + lane];
        float v7 = yin[(s7 << 6) + lane];
        acc += ((v0 + v1) + (v2 + v3)) + ((v4 + v5) + (v6 + v7));
    }
    for (; j < end; ++j) acc += yin[(src_s[j] << 6) + lane];

    float dn = dis[node];
    float x  = dn * acc;                 // x_{l+1}
    int o = (node << 6) + lane;
    if (mode == 0) {
        yout[o] = dn * x;
        outw[o] = alpha * (emb[o] + x);
    } else if (mode == 1) {
        yout[o] = dn * x;
        outw[o] += alpha * x;
    } else {
        outw[o] += alpha * x;
    }
}

// 16 queries per wave, 4 lanes per query, float4 row loads.
__global__ __launch_bounds__(256) void score_kernel(
        const int* __restrict__ qa, const int* __restrict__ qb,
        const float4* __restrict__ x4, float* __restrict__ res) {
    int wave = (blockIdx.x * blockDim.x + threadIdx.x) >> 6;
    int lane = threadIdx.x & 63;
    int g = lane >> 2;                   // query slot in wave (0..15)
    int k = lane & 3;                    // chunk lane (0..3)
    int q = (wave << 4) + g;
    int a = qa[q];
    int b = qb[q];
    const float4* pa = x4 + (a << 4);    // 16 float4s per row
    const float4* pb = x4 + (b << 4);
    float4 a0 = pa[k];      float4 b0 = pb[k];
    float4 a1 = pa[4 + k];  float4 b1 = pb[4 + k];
    float4 a2 = pa[8 + k];  float4 b2 = pb[8 + k];
    float4 a3 = pa[12 + k]; float4 b3 = pb[12 + k];
    float p = a0.x * b0.x;
    p = fmaf(a0.y, b0.y, p); p = fmaf(a0.z, b0.z, p); p = fmaf(a0.w, b0.w, p);
    p = fmaf(a1.x, b1.x, p); p = fmaf(a1.y, b1.y, p);
    p = fmaf(a1.z, b1.z, p); p = fmaf(a1.w, b1.w, p);
    p = fmaf(a2.x, b2.x, p); p = fmaf(a2.y, b2.y, p);
    p = fmaf(a2.z, b2.z, p); p = fmaf(a2.w, b2.w, p);
    p = fmaf(a3.x, b3.x, p); p = fmaf(a3.y, b3.y, p);
    p = fmaf(a3.z, b3.z, p); p = fmaf(a3.w, b3.w, p);
    p += __shfl_xor(p, 1);
    p += __shfl_xor(p, 2);
    if (k == 0) res[q] = p;
}

extern "C" void kernel_launch(void* const* d_in, const int* in_sizes, int n_in,
                              void* d_out, int out_size, void* d_ws, size_t ws_size,
                              hipStream_t stream) {
    const float* emb  = (const float*)d_in[0];
    const int*   edge = (const int*)d_in[1];   // [2][NUM_EDGES]: src then dst
    const int*   qidx = (const int*)d_in[2];   // [2][NUM_QUERY]
    float*       out  = (float*)d_out;         // [NUM_QUERY]

    const int* e_src = edge;
    const int* e_dst = edge + NUM_EDGES;
    const int* q_a   = qidx;
    const int* q_b   = qidx + NUM_QUERY;

    const size_t XBYTES = (size_t)NUM_NODES * EMB_DIM * sizeof(float); // 25.6 MB
    char* ws = (char*)d_ws;
    size_t off = 0;
    auto carve = [&](size_t bytes) { void* p = ws + off; off += (bytes + 255) & ~(size_t)255; return p; };
    int*   hist_g  = (int*)  carve((size_t)NCHUNK * NBUCKETS * 4);   // 800 KB (reused A/B)
    int*   bcnt    = (int*)  carve((size_t)NBUCKETS * 4);
    int*   boffs   = (int*)  carve((size_t)(NBUCKETS + 1) * 4);      // reused A/B
    int*   offs    = (int*)  carve((size_t)(NUM_NODES + 1) * 4);
    float* dis     = (float*)carve((size_t)NUM_NODES * 4);
    int*   deg_n   = (int*)  carve((size_t)NUM_NODES * 4);
    int*   dh      = (int*)  carve((size_t)DCHUNKS * DBINS * 4);     // 32 KB
    int*   perm    = (int*)  carve((size_t)NUM_NODES * 4);
    int2*  pairs   = (int2*) carve((size_t)NUM_EDGES * 8);   // 25.6 MB
    int*   packed  = (int*)  carve((size_t)NUM_EDGES * 4);   // 12.8 MB
    float* yA      = (float*)carve(XBYTES);
    float* yB      = (float*)carve(XBYTES);
    float* outw    = (float*)carve(XBYTES);
    int*   src_srt = (int*)pairs;        // pairs dead after cscatter_kernel

    const float alpha = 1.0f / (NUM_LAYERS + 1);   // 0.25

    // ---- Pass A: coarse src-major sort (int2 pairs, single-store frontier)
    chist_kernel<<<NCHUNK, 256, 0, stream>>>(e_src, hist_g);
    bscan_kernel<<<(NBUCKETS * 64 + 255) / 256, 256, 0, stream>>>(hist_g, bcnt);
    scan_kernel<<<1, 1024, 0, stream>>>(bcnt, boffs);
    cscatter2_kernel<<<NCHUNK, 256, 0, stream>>>(e_src, e_dst, boffs, hist_g, pairs);

    // ---- Pass B: dst-major sort of the src-ordered pairs -> per-node CSR
    chist_pairs_kernel<<<NCHUNK, 256, 0, stream>>>(pairs, hist_g);
    bscan_kernel<<<(NBUCKETS * 64 + 255) / 256, 256, 0, stream>>>(hist_g, bcnt);
    scan_kernel<<<1, 1024, 0, stream>>>(bcnt, boffs);
    cscatter_kernel<<<NCHUNK, 256, 0, stream>>>(pairs, boffs, hist_g, packed);
    lsort_kernel<<<NBUCKETS, 256, 0, stream>>>(boffs, packed, offs, src_srt, dis, deg_n);

    // ---- degree-grouped node permutation
    dhist_kernel<<<DCHUNKS, 256, 0, stream>>>(deg_n, dh);
    dscan_kernel<<<1, 128, 0, stream>>>(dh);
    dscatter_kernel<<<DCHUNKS, 256, 0, stream>>>(deg_n, dh, perm);

    prescale_kernel<<<2048, 256, 0, stream>>>((const float4*)emb, dis, (float4*)yA);

    // ---- 3 propagation layers (y-space), out-accumulation fused
    const int PROP_BLOCKS = (NUM_NODES * 64 + 255) / 256;
    prop_kernel<<<PROP_BLOCKS, 256, 0, stream>>>(perm, offs, src_srt, dis, yA, yB, emb, outw, alpha, 0);
    prop_kernel<<<PROP_BLOCKS, 256, 0, stream>>>(perm, offs, src_srt, dis, yB, yA, emb, outw, alpha, 1);
    prop_kernel<<<PROP_BLOCKS, 256, 0, stream>>>(perm, offs, src_srt, dis, yA, yB, emb, outw, alpha, 2);

    // ---- scoring: 64 queries per 256-thread block (16 per wave)
    score_kernel<<<NUM_QUERY / 64, 256, 0, stream>>>(q_a, q_b, (const float4*)outw, out);
}

// Round 10
// 408.121 us; speedup vs baseline: 1.5036x; 1.4882x over previous
//
#include <hip/hip_runtime.h>
#include <hip/hip_fp16.h>

#define NUM_NODES 100000
#define EMB_DIM   64
#define NUM_LAYERS 3
#define NUM_EDGES 3200000
#define NUM_QUERY 1000000

#define BSHIFT   6
#define BNODES   64                                    // nodes per bucket
#define NBUCKETS ((NUM_NODES + BNODES - 1) / BNODES)   // 1563
#define SRC_MASK 131071                                // 17 bits (NUM_NODES < 2^17)
#define NCHUNK   128
#define CHUNK    (NUM_EDGES / NCHUNK)                  // 25000 edges per chunk

// ---------------------------------------------------------------------------
// Pass 1: per-chunk bucket histogram in LDS -> hist_g[chunk][bucket]
__global__ __launch_bounds__(256) void chist_kernel(const int* __restrict__ dst,
                                                    int* __restrict__ hist_g) {
    __shared__ int h[NBUCKETS];
    int b = blockIdx.x, tid = threadIdx.x;
    for (int k = tid; k < NBUCKETS; k += 256) h[k] = 0;
    __syncthreads();
    int beg = b * CHUNK, end = beg + CHUNK;
    for (int i = beg + tid; i < end; i += 256)
        atomicAdd(&h[dst[i] >> BSHIFT], 1);
    __syncthreads();
    for (int k = tid; k < NBUCKETS; k += 256)
        hist_g[b * NBUCKETS + k] = h[k];
}

// Per-bucket exclusive scan across the 128 chunks (one wave per bucket, in place).
__global__ void bscan_kernel(int* __restrict__ hist_g, int* __restrict__ bcnt) {
    int gw   = (blockIdx.x * blockDim.x + threadIdx.x) >> 6;
    int lane = threadIdx.x & 63;
    if (gw >= NBUCKETS) return;
    int c0 = 2 * lane, c1 = 2 * lane + 1;
    int v0 = hist_g[c0 * NBUCKETS + gw];
    int v1 = hist_g[c1 * NBUCKETS + gw];
    int pair = v0 + v1, x = pair;
    #pragma unroll
    for (int d = 1; d < 64; d <<= 1) {
        int y = __shfl_up(x, d);
        if (lane >= d) x += y;
    }
    int ex = x - pair;                    // exclusive prefix over chunks
    hist_g[c0 * NBUCKETS + gw] = ex;
    hist_g[c1 * NBUCKETS + gw] = ex + v0;
    if (lane == 63) bcnt[gw] = x;         // bucket total
}

// single-block scan over NBUCKETS (2 tiles): boffs[b+1] = inclusive sum
__global__ void scan_kernel(const int* __restrict__ bcnt, int* __restrict__ boffs) {
    __shared__ int tile[1024];
    __shared__ int carry;
    int t = threadIdx.x;
    if (t == 0) { carry = 0; boffs[0] = 0; }
    __syncthreads();
    for (int base = 0; base < NBUCKETS; base += 1024) {
        int v = (base + t < NBUCKETS) ? bcnt[base + t] : 0;
        tile[t] = v;
        __syncthreads();
        for (int d = 1; d < 1024; d <<= 1) {
            int add = (t >= d) ? tile[t - d] : 0;
            __syncthreads();
            tile[t] += add;
            __syncthreads();
        }
        int inc = tile[t] + carry;
        if (base + t < NBUCKETS) boffs[base + t + 1] = inc;
        __syncthreads();
        if (t == 1023) carry = inc;
        __syncthreads();
    }
}

// Pass 2: scatter via LDS cursors — every (chunk,bucket) segment is written by
// exactly one block (one XCD), killing cross-XCD line ping-pong.
__global__ __launch_bounds__(256) void cscatter_kernel(
        const int* __restrict__ src, const int* __restrict__ dst,
        const int* __restrict__ boffs, const int* __restrict__ hist_g,
        int* __restrict__ packed) {
    __shared__ int cur[NBUCKETS];
    int b = blockIdx.x, tid = threadIdx.x;
    for (int k = tid; k < NBUCKETS; k += 256)
        cur[k] = boffs[k] + hist_g[b * NBUCKETS + k];
    __syncthreads();
    int beg = b * CHUNK, end = beg + CHUNK;
    for (int i = beg + tid; i < end; i += 256) {
        int s = src[i], d = dst[i];
        int pos = atomicAdd(&cur[d >> BSHIFT], 1);
        packed[pos] = s | ((d & 63) << 17);
    }
}

// per-bucket local counting sort -> exact per-node CSR (src_srt, offs) + dis
__global__ __launch_bounds__(256) void lsort_kernel(
        const int* __restrict__ boffs, const int* __restrict__ packed,
        int* __restrict__ offs, int* __restrict__ src_srt, float* __restrict__ dis) {
    __shared__ int cnt[BNODES];
    int b   = blockIdx.x;
    int tid = threadIdx.x;
    int beg = boffs[b];
    int end = boffs[b + 1];
    if (tid < BNODES) cnt[tid] = 0;
    __syncthreads();
    for (int i = beg + tid; i < end; i += 256)
        atomicAdd(&cnt[(packed[i] >> 17) & 63], 1);
    __syncthreads();
    if (tid < 64) {                      // wave 0: exclusive scan of 64 counters
        int v = cnt[tid];
        int x = v;
        #pragma unroll
        for (int d = 1; d < 64; d <<= 1) {
            int y = __shfl_up(x, d);
            if (tid >= d) x += y;
        }
        int ex = x - v;                  // exclusive prefix
        int node = (b << BSHIFT) + tid;
        if (node <= NUM_NODES) offs[node] = beg + ex;   // bucket 1562/tid 32 writes offs[N]=E
        if (node <  NUM_NODES) dis[node] = (v > 0) ? rsqrtf((float)v) : 0.0f;
        cnt[tid] = ex;                   // reuse as local cursor
    }
    __syncthreads();
    for (int i = beg + tid; i < end; i += 256) {
        int p  = packed[i];
        int pos = beg + atomicAdd(&cnt[(p >> 17) & 63], 1);
        src_srt[pos] = p & SRC_MASK;
    }
}

// y = fp16(dis ⊙ emb), float4 in, half2 out
__global__ void prescale_kernel(const float4* __restrict__ emb4, const float* __restrict__ dis,
                                __half2* __restrict__ y2) {
    int i = blockIdx.x * blockDim.x + threadIdx.x;
    int stride = gridDim.x * blockDim.x;
    const int n4 = NUM_NODES * EMB_DIM / 4;
    for (; i < n4; i += stride) {
        float d = dis[i >> 4];               // 16 float4s per row
        float4 v = emb4[i];
        y2[2 * i]     = __floats2half2_rn(v.x * d, v.y * d);
        y2[2 * i + 1] = __floats2half2_rn(v.z * d, v.w * d);
    }
}

// ---------------------------------------------------------------------------
// Wave per node, lane = dim, exact CSR gather, zero atomics, y-space (fp16
// storage, fp32 accumulation). Gathered rows are 128 B instead of 256 B.
//  mode 0: yout = h(dn*x); outw = h(alpha*(emb + x))
//  mode 1: yout = h(dn*x); outw += alpha*x
//  mode 2:                 outw += alpha*x
__global__ __launch_bounds__(256) void prop_kernel(
        const int* __restrict__ offs, const int* __restrict__ src_s,
        const float* __restrict__ dis, const __half* __restrict__ yin,
        __half* __restrict__ yout, const float* __restrict__ emb,
        __half* __restrict__ outw, float alpha, int mode) {
    int wid  = (blockIdx.x * blockDim.x + threadIdx.x) >> 6;
    int lane = threadIdx.x & 63;
    if (wid >= NUM_NODES) return;
    int beg = offs[wid];
    int end = offs[wid + 1];
    float acc = 0.0f;
    int j = beg;
    // 8-deep gather pipeline
    for (; j + 8 <= end; j += 8) {
        int s0 = src_s[j];     int s1 = src_s[j + 1];
        int s2 = src_s[j + 2]; int s3 = src_s[j + 3];
        int s4 = src_s[j + 4]; int s5 = src_s[j + 5];
        int s6 = src_s[j + 6]; int s7 = src_s[j + 7];
        float v0 = __half2float(yin[(s0 << 6) + lane]);
        float v1 = __half2float(yin[(s1 << 6) + lane]);
        float v2 = __half2float(yin[(s2 << 6) + lane]);
        float v3 = __half2float(yin[(s3 << 6) + lane]);
        float v4 = __half2float(yin[(s4 << 6) + lane]);
        float v5 = __half2float(yin[(s5 << 6) + lane]);
        float v6 = __half2float(yin[(s6 << 6) + lane]);
        float v7 = __half2float(yin[(s7 << 6) + lane]);
        acc += ((v0 + v1) + (v2 + v3)) + ((v4 + v5) + (v6 + v7));
    }
    for (; j < end; ++j) acc += __half2float(yin[(src_s[j] << 6) + lane]);

    float dn = dis[wid];
    float x  = dn * acc;                 // x_{l+1}
    int o = (wid << 6) + lane;
    if (mode == 0) {
        yout[o] = __float2half(dn * x);
        outw[o] = __float2half(alpha * (emb[o] + x));
    } else if (mode == 1) {
        yout[o] = __float2half(dn * x);
        float w = __half2float(outw[o]);
        outw[o] = __float2half(fmaf(alpha, x, w));
    } else {
        float w = __half2float(outw[o]);
        outw[o] = __float2half(fmaf(alpha, x, w));
    }
}

// 16 queries per wave, 4 lanes per query, fp16 rows (128 B), fp32 accumulate.
// Lane k (0..3) reads uint4 #k and #(k+4) of the 8-uint4 row.
__global__ __launch_bounds__(256) void score_kernel(
        const int* __restrict__ qa, const int* __restrict__ qb,
        const uint4* __restrict__ x4, float* __restrict__ res) {
    int wave = (blockIdx.x * blockDim.x + threadIdx.x) >> 6;
    int lane = threadIdx.x & 63;
    int g = lane >> 2;                   // query slot in wave (0..15)
    int k = lane & 3;                    // chunk lane (0..3)
    int q = (wave << 4) + g;
    int a = qa[q];
    int b = qb[q];
    const uint4* pa = x4 + (a << 3);     // 8 uint4 (= 64 halves) per row
    const uint4* pb = x4 + (b << 3);
    uint4 ua0 = pa[k];     uint4 ub0 = pb[k];
    uint4 ua1 = pa[4 + k]; uint4 ub1 = pb[4 + k];
    float p = 0.0f;
    {
        const unsigned* wa = &ua0.x;
        const unsigned* wb = &ub0.x;
        #pragma unroll
        for (int t = 0; t < 4; ++t) {
            float2 fa = __half22float2(*(const __half2*)&wa[t]);
            float2 fb = __half22float2(*(const __half2*)&wb[t]);
            p = fmaf(fa.x, fb.x, p);
            p = fmaf(fa.y, fb.y, p);
        }
        const unsigned* va = &ua1.x;
        const unsigned* vb = &ub1.x;
        #pragma unroll
        for (int t = 0; t < 4; ++t) {
            float2 fa = __half22float2(*(const __half2*)&va[t]);
            float2 fb = __half22float2(*(const __half2*)&vb[t]);
            p = fmaf(fa.x, fb.x, p);
            p = fmaf(fa.y, fb.y, p);
        }
    }
    p += __shfl_xor(p, 1);
    p += __shfl_xor(p, 2);
    if (k == 0) res[q] = p;
}

extern "C" void kernel_launch(void* const* d_in, const int* in_sizes, int n_in,
                              void* d_out, int out_size, void* d_ws, size_t ws_size,
                              hipStream_t stream) {
    const float* emb  = (const float*)d_in[0];
    const int*   edge = (const int*)d_in[1];   // [2][NUM_EDGES]: src then dst
    const int*   qidx = (const int*)d_in[2];   // [2][NUM_QUERY]
    float*       out  = (float*)d_out;         // [NUM_QUERY]

    const int* e_src = edge;
    const int* e_dst = edge + NUM_EDGES;
    const int* q_a   = qidx;
    const int* q_b   = qidx + NUM_QUERY;

    const size_t HBYTES = (size_t)NUM_NODES * EMB_DIM * sizeof(__half); // 12.8 MB
    char* ws = (char*)d_ws;
    size_t off = 0;
    auto carve = [&](size_t bytes) { void* p = ws + off; off += (bytes + 255) & ~(size_t)255; return p; };
    int*    hist_g  = (int*)   carve((size_t)NCHUNK * NBUCKETS * 4);   // 800 KB
    int*    bcnt    = (int*)   carve((size_t)NBUCKETS * 4);
    int*    boffs   = (int*)   carve((size_t)(NBUCKETS + 1) * 4);
    int*    offs    = (int*)   carve((size_t)(NUM_NODES + 1) * 4);
    float*  dis     = (float*) carve((size_t)NUM_NODES * 4);
    int*    packed  = (int*)   carve((size_t)NUM_EDGES * 4);   // 12.8 MB
    int*    src_srt = (int*)   carve((size_t)NUM_EDGES * 4);   // 12.8 MB
    __half* yA      = (__half*)carve(HBYTES);
    __half* yB      = (__half*)carve(HBYTES);
    __half* outw    = (__half*)carve(HBYTES);

    const float alpha = 1.0f / (NUM_LAYERS + 1);   // 0.25

    // ---- build exact dst-sorted CSR: chunked counting sort, zero global atomics
    chist_kernel<<<NCHUNK, 256, 0, stream>>>(e_dst, hist_g);
    bscan_kernel<<<(NBUCKETS * 64 + 255) / 256, 256, 0, stream>>>(hist_g, bcnt);
    scan_kernel<<<1, 1024, 0, stream>>>(bcnt, boffs);
    cscatter_kernel<<<NCHUNK, 256, 0, stream>>>(e_src, e_dst, boffs, hist_g, packed);
    lsort_kernel<<<NBUCKETS, 256, 0, stream>>>(boffs, packed, offs, src_srt, dis);
    prescale_kernel<<<2048, 256, 0, stream>>>((const float4*)emb, dis, (__half2*)yA);

    // ---- 3 propagation layers (fp16 storage, fp32 math), out-accumulation fused
    const int PROP_BLOCKS = (NUM_NODES * 64 + 255) / 256;
    prop_kernel<<<PROP_BLOCKS, 256, 0, stream>>>(offs, src_srt, dis, yA, yB, emb, outw, alpha, 0);
    prop_kernel<<<PROP_BLOCKS, 256, 0, stream>>>(offs, src_srt, dis, yB, yA, emb, outw, alpha, 1);
    prop_kernel<<<PROP_BLOCKS, 256, 0, stream>>>(offs, src_srt, dis, yA, yB, emb, outw, alpha, 2);

    // ---- scoring: 64 queries per 256-thread block (16 per wave)
    score_kernel<<<NUM_QUERY / 64, 256, 0, stream>>>(q_a, q_b, (const uint4*)outw, out);
}

// Round 11
// 364.128 us; speedup vs baseline: 1.6853x; 1.1208x over previous
//
#include <hip/hip_runtime.h>
#include <hip/hip_fp16.h>

#define NUM_NODES 100000
#define EMB_DIM   64
#define NUM_LAYERS 3
#define NUM_EDGES 3200000
#define NUM_QUERY 1000000

#define BSHIFT   6
#define BNODES   64                                    // nodes per bucket
#define NBUCKETS ((NUM_NODES + BNODES - 1) / BNODES)   // 1563
#define SRC_MASK 131071                                // 17 bits (NUM_NODES < 2^17)
#define NCHUNK   128
#define CHUNK    (NUM_EDGES / NCHUNK)                  // 25000 edges per chunk

// ---------------------------------------------------------------------------
// Pass 1: per-chunk bucket histogram in LDS -> hist_g[chunk][bucket]
__global__ __launch_bounds__(256) void chist_kernel(const int* __restrict__ dst,
                                                    int* __restrict__ hist_g) {
    __shared__ int h[NBUCKETS];
    int b = blockIdx.x, tid = threadIdx.x;
    for (int k = tid; k < NBUCKETS; k += 256) h[k] = 0;
    __syncthreads();
    int beg = b * CHUNK, end = beg + CHUNK;
    for (int i = beg + tid; i < end; i += 256)
        atomicAdd(&h[dst[i] >> BSHIFT], 1);
    __syncthreads();
    for (int k = tid; k < NBUCKETS; k += 256)
        hist_g[b * NBUCKETS + k] = h[k];
}

// Per-bucket exclusive scan across the 128 chunks (one wave per bucket, in place).
__global__ void bscan_kernel(int* __restrict__ hist_g, int* __restrict__ bcnt) {
    int gw   = (blockIdx.x * blockDim.x + threadIdx.x) >> 6;
    int lane = threadIdx.x & 63;
    if (gw >= NBUCKETS) return;
    int c0 = 2 * lane, c1 = 2 * lane + 1;
    int v0 = hist_g[c0 * NBUCKETS + gw];
    int v1 = hist_g[c1 * NBUCKETS + gw];
    int pair = v0 + v1, x = pair;
    #pragma unroll
    for (int d = 1; d < 64; d <<= 1) {
        int y = __shfl_up(x, d);
        if (lane >= d) x += y;
    }
    int ex = x - pair;                    // exclusive prefix over chunks
    hist_g[c0 * NBUCKETS + gw] = ex;
    hist_g[c1 * NBUCKETS + gw] = ex + v0;
    if (lane == 63) bcnt[gw] = x;         // bucket total
}

// single-block scan over NBUCKETS (2 tiles): boffs[b+1] = inclusive sum
__global__ void scan_kernel(const int* __restrict__ bcnt, int* __restrict__ boffs) {
    __shared__ int tile[1024];
    __shared__ int carry;
    int t = threadIdx.x;
    if (t == 0) { carry = 0; boffs[0] = 0; }
    __syncthreads();
    for (int base = 0; base < NBUCKETS; base += 1024) {
        int v = (base + t < NBUCKETS) ? bcnt[base + t] : 0;
        tile[t] = v;
        __syncthreads();
        for (int d = 1; d < 1024; d <<= 1) {
            int add = (t >= d) ? tile[t - d] : 0;
            __syncthreads();
            tile[t] += add;
            __syncthreads();
        }
        int inc = tile[t] + carry;
        if (base + t < NBUCKETS) boffs[base + t + 1] = inc;
        __syncthreads();
        if (t == 1023) carry = inc;
        __syncthreads();
    }
}

// Pass 2: scatter via LDS cursors — every (chunk,bucket) segment is written by
// exactly one block (one XCD), killing cross-XCD line ping-pong.
__global__ __launch_bounds__(256) void cscatter_kernel(
        const int* __restrict__ src, const int* __restrict__ dst,
        const int* __restrict__ boffs, const int* __restrict__ hist_g,
        int* __restrict__ packed) {
    __shared__ int cur[NBUCKETS];
    int b = blockIdx.x, tid = threadIdx.x;
    for (int k = tid; k < NBUCKETS; k += 256)
        cur[k] = boffs[k] + hist_g[b * NBUCKETS + k];
    __syncthreads();
    int beg = b * CHUNK, end = beg + CHUNK;
    for (int i = beg + tid; i < end; i += 256) {
        int s = src[i], d = dst[i];
        int pos = atomicAdd(&cur[d >> BSHIFT], 1);
        packed[pos] = s | ((d & 63) << 17);
    }
}

// per-bucket local counting sort -> exact per-node CSR (src_srt, offs) + dis
__global__ __launch_bounds__(256) void lsort_kernel(
        const int* __restrict__ boffs, const int* __restrict__ packed,
        int* __restrict__ offs, int* __restrict__ src_srt, float* __restrict__ dis) {
    __shared__ int cnt[BNODES];
    int b   = blockIdx.x;
    int tid = threadIdx.x;
    int beg = boffs[b];
    int end = boffs[b + 1];
    if (tid < BNODES) cnt[tid] = 0;
    __syncthreads();
    for (int i = beg + tid; i < end; i += 256)
        atomicAdd(&cnt[(packed[i] >> 17) & 63], 1);
    __syncthreads();
    if (tid < 64) {                      // wave 0: exclusive scan of 64 counters
        int v = cnt[tid];
        int x = v;
        #pragma unroll
        for (int d = 1; d < 64; d <<= 1) {
            int y = __shfl_up(x, d);
            if (tid >= d) x += y;
        }
        int ex = x - v;                  // exclusive prefix
        int node = (b << BSHIFT) + tid;
        if (node <= NUM_NODES) offs[node] = beg + ex;   // bucket 1562/tid 32 writes offs[N]=E
        if (node <  NUM_NODES) dis[node] = (v > 0) ? rsqrtf((float)v) : 0.0f;
        cnt[tid] = ex;                   // reuse as local cursor
    }
    __syncthreads();
    for (int i = beg + tid; i < end; i += 256) {
        int p  = packed[i];
        int pos = beg + atomicAdd(&cnt[(p >> 17) & 63], 1);
        src_srt[pos] = p & SRC_MASK;
    }
}

// y = fp16(dis ⊙ emb), float4 in, half2 out
__global__ void prescale_kernel(const float4* __restrict__ emb4, const float* __restrict__ dis,
                                __half2* __restrict__ y2) {
    int i = blockIdx.x * blockDim.x + threadIdx.x;
    int stride = gridDim.x * blockDim.x;
    const int n4 = NUM_NODES * EMB_DIM / 4;
    for (; i < n4; i += stride) {
        float d = dis[i >> 4];               // 16 float4s per row
        float4 v = emb4[i];
        y2[2 * i]     = __floats2half2_rn(v.x * d, v.y * d);
        y2[2 * i + 1] = __floats2half2_rn(v.z * d, v.w * d);
    }
}

// ---------------------------------------------------------------------------
// Wave per node. half2 lanes: lane = (edge parity: lane>>5, dim pair: lane&31).
// One half2 gather instruction covers TWO edges (2 x 128 B rows). fp32 accum.
// Cross-half merge via one shfl_xor(32) pair at the end; writeout splits
// lanes 0-31 -> yout, lanes 32-63 -> outw RMW (parallel, not serial).
//  mode 0: yout = h(dn*x); outw = h(alpha*(emb + x))
//  mode 1: yout = h(dn*x); outw += alpha*x
//  mode 2:                 outw += alpha*x
__global__ __launch_bounds__(256) void prop_kernel(
        const int* __restrict__ offs, const int* __restrict__ src_s,
        const float* __restrict__ dis, const __half2* __restrict__ yin2,
        __half2* __restrict__ yout2, const float2* __restrict__ emb2,
        __half2* __restrict__ outw2, float alpha, int mode) {
    int wid  = (blockIdx.x * blockDim.x + threadIdx.x) >> 6;
    int lane = threadIdx.x & 63;
    if (wid >= NUM_NODES) return;
    int sub = lane & 31;                 // dim pair
    int par = lane >> 5;                 // edge parity (0/1)
    int beg = offs[wid];
    int end = offs[wid + 1];
    float ax = 0.0f, ay = 0.0f;
    int j = beg;
    // 8 edges per iteration: each lane gathers 4 half2 (its parity's edges)
    for (; j + 8 <= end; j += 8) {
        int s0 = src_s[j + 0 + par];
        int s1 = src_s[j + 2 + par];
        int s2 = src_s[j + 4 + par];
        int s3 = src_s[j + 6 + par];
        __half2 h0 = yin2[(s0 << 5) + sub];
        __half2 h1 = yin2[(s1 << 5) + sub];
        __half2 h2 = yin2[(s2 << 5) + sub];
        __half2 h3 = yin2[(s3 << 5) + sub];
        float2 f0 = __half22float2(h0);
        float2 f1 = __half22float2(h1);
        float2 f2 = __half22float2(h2);
        float2 f3 = __half22float2(h3);
        ax += (f0.x + f1.x) + (f2.x + f3.x);
        ay += (f0.y + f1.y) + (f2.y + f3.y);
    }
    // pair tail
    for (; j + 2 <= end; j += 2) {
        int s = src_s[j + par];
        float2 f = __half22float2(yin2[(s << 5) + sub]);
        ax += f.x; ay += f.y;
    }
    // odd single edge: parity-0 lanes only
    if (j < end && par == 0) {
        int s = src_s[j];
        float2 f = __half22float2(yin2[(s << 5) + sub]);
        ax += f.x; ay += f.y;
    }
    // merge the two parity streams
    ax += __shfl_xor(ax, 32);
    ay += __shfl_xor(ay, 32);

    float dn = dis[wid];
    float xx = dn * ax, xy = dn * ay;    // x_{l+1} dim pair
    int o2 = (wid << 5) + sub;
    if (mode == 0) {
        if (par == 0) {
            yout2[o2] = __floats2half2_rn(dn * xx, dn * xy);
        } else {
            float2 e = emb2[o2];
            outw2[o2] = __floats2half2_rn(alpha * (e.x + xx), alpha * (e.y + xy));
        }
    } else if (mode == 1) {
        if (par == 0) {
            yout2[o2] = __floats2half2_rn(dn * xx, dn * xy);
        } else {
            float2 w = __half22float2(outw2[o2]);
            outw2[o2] = __floats2half2_rn(fmaf(alpha, xx, w.x), fmaf(alpha, xy, w.y));
        }
    } else {
        if (par == 1) {
            float2 w = __half22float2(outw2[o2]);
            outw2[o2] = __floats2half2_rn(fmaf(alpha, xx, w.x), fmaf(alpha, xy, w.y));
        }
    }
}

// ---------------------------------------------------------------------------
// packed fp16 dot-accumulate: v_dot2_f32_f16 where available, float2 fallback
#if defined(__has_builtin)
#if __has_builtin(__builtin_amdgcn_fdot2)
#define HAVE_FDOT2 1
#endif
#endif

#ifdef HAVE_FDOT2
typedef _Float16 hv2 __attribute__((ext_vector_type(2)));
__device__ __forceinline__ float dot2acc(unsigned a, unsigned b, float c) {
    hv2 ha, hb;
    __builtin_memcpy(&ha, &a, 4);
    __builtin_memcpy(&hb, &b, 4);
    return __builtin_amdgcn_fdot2(ha, hb, c, false);
}
#else
__device__ __forceinline__ float dot2acc(unsigned a, unsigned b, float c) {
    float2 fa = __half22float2(*(const __half2*)&a);
    float2 fb = __half22float2(*(const __half2*)&b);
    return fmaf(fa.y, fb.y, fmaf(fa.x, fb.x, c));
}
#endif

// 16 queries per wave, 4 lanes per query, fp16 rows (128 B), fp32 accumulate.
__global__ __launch_bounds__(256) void score_kernel(
        const int* __restrict__ qa, const int* __restrict__ qb,
        const uint4* __restrict__ x4, float* __restrict__ res) {
    int wave = (blockIdx.x * blockDim.x + threadIdx.x) >> 6;
    int lane = threadIdx.x & 63;
    int g = lane >> 2;                   // query slot in wave (0..15)
    int k = lane & 3;                    // chunk lane (0..3)
    int q = (wave << 4) + g;
    int a = qa[q];
    int b = qb[q];
    const uint4* pa = x4 + (a << 3);     // 8 uint4 (= 64 halves) per row
    const uint4* pb = x4 + (b << 3);
    uint4 ua0 = pa[k];     uint4 ub0 = pb[k];
    uint4 ua1 = pa[4 + k]; uint4 ub1 = pb[4 + k];
    float p = 0.0f;
    p = dot2acc(ua0.x, ub0.x, p);
    p = dot2acc(ua0.y, ub0.y, p);
    p = dot2acc(ua0.z, ub0.z, p);
    p = dot2acc(ua0.w, ub0.w, p);
    p = dot2acc(ua1.x, ub1.x, p);
    p = dot2acc(ua1.y, ub1.y, p);
    p = dot2acc(ua1.z, ub1.z, p);
    p = dot2acc(ua1.w, ub1.w, p);
    p += __shfl_xor(p, 1);
    p += __shfl_xor(p, 2);
    if (k == 0) res[q] = p;
}

extern "C" void kernel_launch(void* const* d_in, const int* in_sizes, int n_in,
                              void* d_out, int out_size, void* d_ws, size_t ws_size,
                              hipStream_t stream) {
    const float* emb  = (const float*)d_in[0];
    const int*   edge = (const int*)d_in[1];   // [2][NUM_EDGES]: src then dst
    const int*   qidx = (const int*)d_in[2];   // [2][NUM_QUERY]
    float*       out  = (float*)d_out;         // [NUM_QUERY]

    const int* e_src = edge;
    const int* e_dst = edge + NUM_EDGES;
    const int* q_a   = qidx;
    const int* q_b   = qidx + NUM_QUERY;

    const size_t HBYTES = (size_t)NUM_NODES * EMB_DIM * sizeof(__half); // 12.8 MB
    char* ws = (char*)d_ws;
    size_t off = 0;
    auto carve = [&](size_t bytes) { void* p = ws + off; off += (bytes + 255) & ~(size_t)255; return p; };
    int*    hist_g  = (int*)   carve((size_t)NCHUNK * NBUCKETS * 4);   // 800 KB
    int*    bcnt    = (int*)   carve((size_t)NBUCKETS * 4);
    int*    boffs   = (int*)   carve((size_t)(NBUCKETS + 1) * 4);
    int*    offs    = (int*)   carve((size_t)(NUM_NODES + 1) * 4);
    float*  dis     = (float*) carve((size_t)NUM_NODES * 4);
    int*    packed  = (int*)   carve((size_t)NUM_EDGES * 4);   // 12.8 MB
    int*    src_srt = (int*)   carve((size_t)NUM_EDGES * 4);   // 12.8 MB
    __half* yA      = (__half*)carve(HBYTES);
    __half* yB      = (__half*)carve(HBYTES);
    __half* outw    = (__half*)carve(HBYTES);

    const float alpha = 1.0f / (NUM_LAYERS + 1);   // 0.25

    // ---- build exact dst-sorted CSR: chunked counting sort, zero global atomics
    chist_kernel<<<NCHUNK, 256, 0, stream>>>(e_dst, hist_g);
    bscan_kernel<<<(NBUCKETS * 64 + 255) / 256, 256, 0, stream>>>(hist_g, bcnt);
    scan_kernel<<<1, 1024, 0, stream>>>(bcnt, boffs);
    cscatter_kernel<<<NCHUNK, 256, 0, stream>>>(e_src, e_dst, boffs, hist_g, packed);
    lsort_kernel<<<NBUCKETS, 256, 0, stream>>>(boffs, packed, offs, src_srt, dis);
    prescale_kernel<<<2048, 256, 0, stream>>>((const float4*)emb, dis, (__half2*)yA);

    // ---- 3 propagation layers (fp16 storage, fp32 math), out-accumulation fused
    const int PROP_BLOCKS = (NUM_NODES * 64 + 255) / 256;
    prop_kernel<<<PROP_BLOCKS, 256, 0, stream>>>(offs, src_srt, dis,
        (const __half2*)yA, (__half2*)yB, (const float2*)emb, (__half2*)outw, alpha, 0);
    prop_kernel<<<PROP_BLOCKS, 256, 0, stream>>>(offs, src_srt, dis,
        (const __half2*)yB, (__half2*)yA, (const float2*)emb, (__half2*)outw, alpha, 1);
    prop_kernel<<<PROP_BLOCKS, 256, 0, stream>>>(offs, src_srt, dis,
        (const __half2*)yA, (__half2*)yB, (const float2*)emb, (__half2*)outw, alpha, 2);

    // ---- scoring: 64 queries per 256-thread block (16 per wave)
    score_kernel<<<NUM_QUERY / 64, 256, 0, stream>>>(q_a, q_b, (const uint4*)outw, out);
}

// Round 12
// 299.366 us; speedup vs baseline: 2.0499x; 1.2163x over previous
//
#include <hip/hip_runtime.h>
#include <hip/hip_fp16.h>

#define NUM_NODES 100000
#define EMB_DIM   64
#define NUM_LAYERS 3
#define NUM_EDGES 3200000
#define NUM_QUERY 1000000

#define BSHIFT   6
#define BNODES   64                                    // nodes per bucket
#define NBUCKETS ((NUM_NODES + BNODES - 1) / BNODES)   // 1563
#define HALF1    782                                   // bucket split point
#define SRC_MASK 131071                                // 17 bits (NUM_NODES < 2^17)
#define NCHUNK   256
#define CHUNK    (NUM_EDGES / NCHUNK)                  // 12500 edges per chunk
#define CHUNK4   (CHUNK / 4)                           // 3125 int4 per chunk

// ---------------------------------------------------------------------------
// Pass 1: per-chunk bucket histogram in LDS -> hist_g[chunk][bucket]
__global__ __launch_bounds__(256) void chist_kernel(const int* __restrict__ keys,
                                                    int* __restrict__ hist_g) {
    __shared__ int h[NBUCKETS];
    int b = blockIdx.x, tid = threadIdx.x;
    for (int k = tid; k < NBUCKETS; k += 256) h[k] = 0;
    __syncthreads();
    const int4* k4 = (const int4*)(keys + b * CHUNK);
    for (int i = tid; i < CHUNK4; i += 256) {
        int4 d = k4[i];
        atomicAdd(&h[d.x >> BSHIFT], 1);
        atomicAdd(&h[d.y >> BSHIFT], 1);
        atomicAdd(&h[d.z >> BSHIFT], 1);
        atomicAdd(&h[d.w >> BSHIFT], 1);
    }
    __syncthreads();
    for (int k = tid; k < NBUCKETS; k += 256)
        hist_g[b * NBUCKETS + k] = h[k];
}

// Per-bucket exclusive scan across the 256 chunks (one wave per bucket, 4/lane).
__global__ void bscan_kernel(int* __restrict__ hist_g, int* __restrict__ bcnt) {
    int gw   = (blockIdx.x * blockDim.x + threadIdx.x) >> 6;
    int lane = threadIdx.x & 63;
    if (gw >= NBUCKETS) return;
    int v0 = hist_g[(4 * lane + 0) * NBUCKETS + gw];
    int v1 = hist_g[(4 * lane + 1) * NBUCKETS + gw];
    int v2 = hist_g[(4 * lane + 2) * NBUCKETS + gw];
    int v3 = hist_g[(4 * lane + 3) * NBUCKETS + gw];
    int quad = v0 + v1 + v2 + v3, x = quad;
    #pragma unroll
    for (int d = 1; d < 64; d <<= 1) {
        int y = __shfl_up(x, d);
        if (lane >= d) x += y;
    }
    int ex = x - quad;                    // exclusive prefix over chunks
    hist_g[(4 * lane + 0) * NBUCKETS + gw] = ex;
    hist_g[(4 * lane + 1) * NBUCKETS + gw] = ex + v0;
    hist_g[(4 * lane + 2) * NBUCKETS + gw] = ex + v0 + v1;
    hist_g[(4 * lane + 3) * NBUCKETS + gw] = ex + v0 + v1 + v2;
    if (lane == 63) bcnt[gw] = x;         // bucket total
}

// single-block scan over NBUCKETS (2 tiles): boffs[b+1] = inclusive sum
__global__ void scan_kernel(const int* __restrict__ bcnt, int* __restrict__ boffs) {
    __shared__ int tile[1024];
    __shared__ int carry;
    int t = threadIdx.x;
    if (t == 0) { carry = 0; boffs[0] = 0; }
    __syncthreads();
    for (int base = 0; base < NBUCKETS; base += 1024) {
        int v = (base + t < NBUCKETS) ? bcnt[base + t] : 0;
        tile[t] = v;
        __syncthreads();
        for (int d = 1; d < 1024; d <<= 1) {
            int add = (t >= d) ? tile[t - d] : 0;
            __syncthreads();
            tile[t] += add;
            __syncthreads();
        }
        int inc = tile[t] + carry;
        if (base + t < NBUCKETS) boffs[base + t + 1] = inc;
        __syncthreads();
        if (t == 1023) carry = inc;
        __syncthreads();
    }
}

// Pass 2: scatter via LDS cursors. 2 blocks per chunk, split by bucket range —
// every (chunk,bucket) segment still has exactly one writer block.
__global__ __launch_bounds__(256) void cscatter_kernel(
        const int* __restrict__ src, const int* __restrict__ dst,
        const int* __restrict__ boffs, const int* __restrict__ hist_g,
        int* __restrict__ packed) {
    __shared__ int cur[NBUCKETS];
    int b = blockIdx.x >> 1, half = blockIdx.x & 1;
    int LO = half ? HALF1 : 0;
    int HI = half ? NBUCKETS : HALF1;
    int tid = threadIdx.x;
    for (int k = tid; k < NBUCKETS; k += 256)
        cur[k] = boffs[k] + hist_g[b * NBUCKETS + k];
    __syncthreads();
    const int4* s4 = (const int4*)(src + b * CHUNK);
    const int4* d4 = (const int4*)(dst + b * CHUNK);
    for (int i = tid; i < CHUNK4; i += 256) {
        int4 s = s4[i];
        int4 d = d4[i];
        int bk;
        bk = d.x >> BSHIFT;
        if (bk >= LO && bk < HI) { int p = atomicAdd(&cur[bk], 1); packed[p] = s.x | ((d.x & 63) << 17); }
        bk = d.y >> BSHIFT;
        if (bk >= LO && bk < HI) { int p = atomicAdd(&cur[bk], 1); packed[p] = s.y | ((d.y & 63) << 17); }
        bk = d.z >> BSHIFT;
        if (bk >= LO && bk < HI) { int p = atomicAdd(&cur[bk], 1); packed[p] = s.z | ((d.z & 63) << 17); }
        bk = d.w >> BSHIFT;
        if (bk >= LO && bk < HI) { int p = atomicAdd(&cur[bk], 1); packed[p] = s.w | ((d.w & 63) << 17); }
    }
}

// per-bucket local counting sort -> exact per-node CSR (src_srt, offs) + dis
__global__ __launch_bounds__(256) void lsort_kernel(
        const int* __restrict__ boffs, const int* __restrict__ packed,
        int* __restrict__ offs, int* __restrict__ src_srt, float* __restrict__ dis) {
    __shared__ int cnt[BNODES];
    int b   = blockIdx.x;
    int tid = threadIdx.x;
    int beg = boffs[b];
    int end = boffs[b + 1];
    if (tid < BNODES) cnt[tid] = 0;
    __syncthreads();
    for (int i = beg + tid; i < end; i += 256)
        atomicAdd(&cnt[(packed[i] >> 17) & 63], 1);
    __syncthreads();
    if (tid < 64) {                      // wave 0: exclusive scan of 64 counters
        int v = cnt[tid];
        int x = v;
        #pragma unroll
        for (int d = 1; d < 64; d <<= 1) {
            int y = __shfl_up(x, d);
            if (tid >= d) x += y;
        }
        int ex = x - v;                  // exclusive prefix
        int node = (b << BSHIFT) + tid;
        if (node <= NUM_NODES) offs[node] = beg + ex;   // bucket 1562/tid 32 writes offs[N]=E
        if (node <  NUM_NODES) dis[node] = (v > 0) ? rsqrtf((float)v) : 0.0f;
        cnt[tid] = ex;                   // reuse as local cursor
    }
    __syncthreads();
    for (int i = beg + tid; i < end; i += 256) {
        int p  = packed[i];
        int pos = beg + atomicAdd(&cnt[(p >> 17) & 63], 1);
        src_srt[pos] = p & SRC_MASK;
    }
}

// y = fp16(dis ⊙ emb), float4 in, half2 out
__global__ void prescale_kernel(const float4* __restrict__ emb4, const float* __restrict__ dis,
                                __half2* __restrict__ y2) {
    int i = blockIdx.x * blockDim.x + threadIdx.x;
    int stride = gridDim.x * blockDim.x;
    const int n4 = NUM_NODES * EMB_DIM / 4;
    for (; i < n4; i += stride) {
        float d = dis[i >> 4];               // 16 float4s per row
        float4 v = emb4[i];
        y2[2 * i]     = __floats2half2_rn(v.x * d, v.y * d);
        y2[2 * i + 1] = __floats2half2_rn(v.z * d, v.w * d);
    }
}

// ---------------------------------------------------------------------------
// Wave per node. half2 lanes: lane = (edge parity: lane>>5, dim pair: lane&31).
// 16-edge main loop -> 8 independent gathers in flight per wave; beg/end are
// readfirstlane'd so index loads are scalar (s_load) and off the VMEM queue.
//  mode 0: yout = h(dn*x); outw = h(alpha*(emb + x))
//  mode 1: yout = h(dn*x); outw += alpha*x
//  mode 2:                 outw += alpha*x
__global__ __launch_bounds__(256) void prop_kernel(
        const int* __restrict__ offs, const int* __restrict__ src_s,
        const float* __restrict__ dis, const __half2* __restrict__ yin2,
        __half2* __restrict__ yout2, const float2* __restrict__ emb2,
        __half2* __restrict__ outw2, float alpha, int mode) {
    int wid  = (blockIdx.x * blockDim.x + threadIdx.x) >> 6;
    int lane = threadIdx.x & 63;
    if (wid >= NUM_NODES) return;
    int sub = lane & 31;                 // dim pair
    int par = lane >> 5;                 // edge parity (0/1)
    int beg = __builtin_amdgcn_readfirstlane(offs[wid]);
    int end = __builtin_amdgcn_readfirstlane(offs[wid + 1]);
    float ax = 0.0f, ay = 0.0f;
    int j = beg;
    // 16 edges per iteration: 8 independent half2 gathers in flight per lane
    for (; j + 16 <= end; j += 16) {
        int i0  = src_s[j + 0],  i1  = src_s[j + 1];
        int i2  = src_s[j + 2],  i3  = src_s[j + 3];
        int i4  = src_s[j + 4],  i5  = src_s[j + 5];
        int i6  = src_s[j + 6],  i7  = src_s[j + 7];
        int i8  = src_s[j + 8],  i9  = src_s[j + 9];
        int i10 = src_s[j + 10], i11 = src_s[j + 11];
        int i12 = src_s[j + 12], i13 = src_s[j + 13];
        int i14 = src_s[j + 14], i15 = src_s[j + 15];
        int s0 = par ? i1  : i0;
        int s1 = par ? i3  : i2;
        int s2 = par ? i5  : i4;
        int s3 = par ? i7  : i6;
        int s4 = par ? i9  : i8;
        int s5 = par ? i11 : i10;
        int s6 = par ? i13 : i12;
        int s7 = par ? i15 : i14;
        __half2 h0 = yin2[(s0 << 5) + sub];
        __half2 h1 = yin2[(s1 << 5) + sub];
        __half2 h2 = yin2[(s2 << 5) + sub];
        __half2 h3 = yin2[(s3 << 5) + sub];
        __half2 h4 = yin2[(s4 << 5) + sub];
        __half2 h5 = yin2[(s5 << 5) + sub];
        __half2 h6 = yin2[(s6 << 5) + sub];
        __half2 h7 = yin2[(s7 << 5) + sub];
        float2 f0 = __half22float2(h0);
        float2 f1 = __half22float2(h1);
        float2 f2 = __half22float2(h2);
        float2 f3 = __half22float2(h3);
        float2 f4 = __half22float2(h4);
        float2 f5 = __half22float2(h5);
        float2 f6 = __half22float2(h6);
        float2 f7 = __half22float2(h7);
        ax += ((f0.x + f1.x) + (f2.x + f3.x)) + ((f4.x + f5.x) + (f6.x + f7.x));
        ay += ((f0.y + f1.y) + (f2.y + f3.y)) + ((f4.y + f5.y) + (f6.y + f7.y));
    }
    // 8-edge block
    if (j + 8 <= end) {
        int i0 = src_s[j + 0], i1 = src_s[j + 1];
        int i2 = src_s[j + 2], i3 = src_s[j + 3];
        int i4 = src_s[j + 4], i5 = src_s[j + 5];
        int i6 = src_s[j + 6], i7 = src_s[j + 7];
        int s0 = par ? i1 : i0;
        int s1 = par ? i3 : i2;
        int s2 = par ? i5 : i4;
        int s3 = par ? i7 : i6;
        __half2 h0 = yin2[(s0 << 5) + sub];
        __half2 h1 = yin2[(s1 << 5) + sub];
        __half2 h2 = yin2[(s2 << 5) + sub];
        __half2 h3 = yin2[(s3 << 5) + sub];
        float2 f0 = __half22float2(h0);
        float2 f1 = __half22float2(h1);
        float2 f2 = __half22float2(h2);
        float2 f3 = __half22float2(h3);
        ax += (f0.x + f1.x) + (f2.x + f3.x);
        ay += (f0.y + f1.y) + (f2.y + f3.y);
        j += 8;
    }
    // pair tail
    for (; j + 2 <= end; j += 2) {
        int s = src_s[j + par];
        float2 f = __half22float2(yin2[(s << 5) + sub]);
        ax += f.x; ay += f.y;
    }
    // odd single edge: parity-0 lanes only
    if (j < end && par == 0) {
        int s = src_s[j];
        float2 f = __half22float2(yin2[(s << 5) + sub]);
        ax += f.x; ay += f.y;
    }
    // merge the two parity streams
    ax += __shfl_xor(ax, 32);
    ay += __shfl_xor(ay, 32);

    float dn = dis[wid];
    float xx = dn * ax, xy = dn * ay;    // x_{l+1} dim pair
    int o2 = (wid << 5) + sub;
    if (mode == 0) {
        if (par == 0) {
            yout2[o2] = __floats2half2_rn(dn * xx, dn * xy);
        } else {
            float2 e = emb2[o2];
            outw2[o2] = __floats2half2_rn(alpha * (e.x + xx), alpha * (e.y + xy));
        }
    } else if (mode == 1) {
        if (par == 0) {
            yout2[o2] = __floats2half2_rn(dn * xx, dn * xy);
        } else {
            float2 w = __half22float2(outw2[o2]);
            outw2[o2] = __floats2half2_rn(fmaf(alpha, xx, w.x), fmaf(alpha, xy, w.y));
        }
    } else {
        if (par == 1) {
            float2 w = __half22float2(outw2[o2]);
            outw2[o2] = __floats2half2_rn(fmaf(alpha, xx, w.x), fmaf(alpha, xy, w.y));
        }
    }
}

// ---------------------------------------------------------------------------
// packed fp16 dot-accumulate: v_dot2_f32_f16 where available, float2 fallback
#if defined(__has_builtin)
#if __has_builtin(__builtin_amdgcn_fdot2)
#define HAVE_FDOT2 1
#endif
#endif

#ifdef HAVE_FDOT2
typedef _Float16 hv2 __attribute__((ext_vector_type(2)));
__device__ __forceinline__ float dot2acc(unsigned a, unsigned b, float c) {
    hv2 ha, hb;
    __builtin_memcpy(&ha, &a, 4);
    __builtin_memcpy(&hb, &b, 4);
    return __builtin_amdgcn_fdot2(ha, hb, c, false);
}
#else
__device__ __forceinline__ float dot2acc(unsigned a, unsigned b, float c) {
    float2 fa = __half22float2(*(const __half2*)&a);
    float2 fb = __half22float2(*(const __half2*)&b);
    return fmaf(fa.y, fb.y, fmaf(fa.x, fb.x, c));
}
#endif

// 16 queries per wave, 4 lanes per query, fp16 rows (128 B), fp32 accumulate.
__global__ __launch_bounds__(256) void score_kernel(
        const int* __restrict__ qa, const int* __restrict__ qb,
        const uint4* __restrict__ x4, float* __restrict__ res) {
    int wave = (blockIdx.x * blockDim.x + threadIdx.x) >> 6;
    int lane = threadIdx.x & 63;
    int g = lane >> 2;                   // query slot in wave (0..15)
    int k = lane & 3;                    // chunk lane (0..3)
    int q = (wave << 4) + g;
    int a = qa[q];
    int b = qb[q];
    const uint4* pa = x4 + (a << 3);     // 8 uint4 (= 64 halves) per row
    const uint4* pb = x4 + (b << 3);
    uint4 ua0 = pa[k];     uint4 ub0 = pb[k];
    uint4 ua1 = pa[4 + k]; uint4 ub1 = pb[4 + k];
    float p = 0.0f;
    p = dot2acc(ua0.x, ub0.x, p);
    p = dot2acc(ua0.y, ub0.y, p);
    p = dot2acc(ua0.z, ub0.z, p);
    p = dot2acc(ua0.w, ub0.w, p);
    p = dot2acc(ua1.x, ub1.x, p);
    p = dot2acc(ua1.y, ub1.y, p);
    p = dot2acc(ua1.z, ub1.z, p);
    p = dot2acc(ua1.w, ub1.w, p);
    p += __shfl_xor(p, 1);
    p += __shfl_xor(p, 2);
    if (k == 0) res[q] = p;
}

extern "C" void kernel_launch(void* const* d_in, const int* in_sizes, int n_in,
                              void* d_out, int out_size, void* d_ws, size_t ws_size,
                              hipStream_t stream) {
    const float* emb  = (const float*)d_in[0];
    const int*   edge = (const int*)d_in[1];   // [2][NUM_EDGES]: src then dst
    const int*   qidx = (const int*)d_in[2];   // [2][NUM_QUERY]
    float*       out  = (float*)d_out;         // [NUM_QUERY]

    const int* e_src = edge;
    const int* e_dst = edge + NUM_EDGES;
    const int* q_a   = qidx;
    const int* q_b   = qidx + NUM_QUERY;

    const size_t HBYTES = (size_t)NUM_NODES * EMB_DIM * sizeof(__half); // 12.8 MB
    char* ws = (char*)d_ws;
    size_t off = 0;
    auto carve = [&](size_t bytes) { void* p = ws + off; off += (bytes + 255) & ~(size_t)255; return p; };
    int*    hist_g  = (int*)   carve((size_t)NCHUNK * NBUCKETS * 4);   // 1.6 MB
    int*    bcnt    = (int*)   carve((size_t)NBUCKETS * 4);
    int*    boffs   = (int*)   carve((size_t)(NBUCKETS + 1) * 4);
    int*    offs    = (int*)   carve((size_t)(NUM_NODES + 1) * 4);
    float*  dis     = (float*) carve((size_t)NUM_NODES * 4);
    int*    packed  = (int*)   carve((size_t)NUM_EDGES * 4);   // 12.8 MB
    int*    src_srt = (int*)   carve((size_t)NUM_EDGES * 4);   // 12.8 MB
    __half* yA      = (__half*)carve(HBYTES);
    __half* yB      = (__half*)carve(HBYTES);
    __half* outw    = (__half*)carve(HBYTES);

    const float alpha = 1.0f / (NUM_LAYERS + 1);   // 0.25

    // ---- build exact dst-sorted CSR: chunked counting sort, zero global atomics
    chist_kernel<<<NCHUNK, 256, 0, stream>>>(e_dst, hist_g);
    bscan_kernel<<<(NBUCKETS * 64 + 255) / 256, 256, 0, stream>>>(hist_g, bcnt);
    scan_kernel<<<1, 1024, 0, stream>>>(bcnt, boffs);
    cscatter_kernel<<<NCHUNK * 2, 256, 0, stream>>>(e_src, e_dst, boffs, hist_g, packed);
    lsort_kernel<<<NBUCKETS, 256, 0, stream>>>(boffs, packed, offs, src_srt, dis);
    prescale_kernel<<<2048, 256, 0, stream>>>((const float4*)emb, dis, (__half2*)yA);

    // ---- 3 propagation layers (fp16 storage, fp32 math), out-accumulation fused
    const int PROP_BLOCKS = (NUM_NODES * 64 + 255) / 256;
    prop_kernel<<<PROP_BLOCKS, 256, 0, stream>>>(offs, src_srt, dis,
        (const __half2*)yA, (__half2*)yB, (const float2*)emb, (__half2*)outw, alpha, 0);
    prop_kernel<<<PROP_BLOCKS, 256, 0, stream>>>(offs, src_srt, dis,
        (const __half2*)yB, (__half2*)yA, (const float2*)emb, (__half2*)outw, alpha, 1);
    prop_kernel<<<PROP_BLOCKS, 256, 0, stream>>>(offs, src_srt, dis,
        (const __half2*)yA, (__half2*)yB, (const float2*)emb, (__half2*)outw, alpha, 2);

    // ---- scoring: 64 queries per 256-thread block (16 per wave)
    score_kernel<<<NUM_QUERY / 64, 256, 0, stream>>>(q_a, q_b, (const uint4*)outw, out);
}